// Round 6
// baseline (431.349 us; speedup 1.0000x reference)
//
#include <hip/hip_runtime.h>
#include <math.h>

typedef __bf16 bf16x8 __attribute__((ext_vector_type(8)));
typedef __bf16 bf16x4 __attribute__((ext_vector_type(4)));
typedef float  f32x4  __attribute__((ext_vector_type(4)));

namespace {
constexpr int L_ = 512, D_ = 512, NF = 11;
constexpr long WE = (long)L_ * L_;   // 262144 elems, one 512x512 plane
constexpr long NE = 8 * WE;          // 2097152 elems, B*L*D
constexpr long CPL = 512L * 1024;    // concatenated plane (512 rows x 1024)
constexpr float NEGV = -1.0e9f;
constexpr float INV_TEMP = 0.044194173824159216f; // 1/sqrt(512)
constexpr unsigned GRID = 256;
}

typedef __attribute__((address_space(1))) void gv_t;
typedef __attribute__((address_space(3))) void lv_t;

__device__ __forceinline__ void async_cp16(const void* g, void* l) {
  __builtin_amdgcn_global_load_lds((gv_t*)g, (lv_t*)l, 16, 0, 0);
}

// Device-scope grid barrier. Counters zeroed by hipMemsetAsync before launch.
// All 256 blocks are guaranteed co-resident (24KB LDS, ~120 VGPR => >=3 blocks/CU capacity).
__device__ __forceinline__ void gbar(unsigned* c) {
  __threadfence();          // release: push this thread's stores to device scope
  __syncthreads();
  if (threadIdx.x == 0) {
    __hip_atomic_fetch_add(c, 1u, __ATOMIC_ACQ_REL, __HIP_MEMORY_SCOPE_AGENT);
    unsigned v;
    do {
      __builtin_amdgcn_s_sleep(2);
      v = __hip_atomic_load(c, __ATOMIC_ACQUIRE, __HIP_MEMORY_SCOPE_AGENT);
    } while (v < GRID);
  }
  __syncthreads();          // blockmates share the CU's L1; t0's acquire covers them
}

// 64x128 NT tile: A [*,K] rows m0..m0+63, B [*,K] rows n0..n0+127, BK=64 as two 32-col panels.
__device__ __forceinline__ void core_nt(const __bf16* __restrict__ A,
                                        const __bf16* __restrict__ B, int K,
                                        int m0, int n0,
                                        __bf16* sA, __bf16* sB, f32x4 (&acc)[2][4])
{
  const int tid = threadIdx.x;
  const int wave = tid >> 6, lane = tid & 63;
  const int prow = wave * 16 + (lane >> 2), pcol = (lane & 3) * 8;
  const int quad = lane >> 4, l16 = lane & 15;
  const int wm = (wave >> 1) * 32, wn = (wave & 1) * 64;
  const __bf16* ga = A + (long)(m0 + prow) * K + pcol;
  const __bf16* gb = B + (long)(n0 + prow) * K + pcol;
  __bf16* dA = sA + prow * 32 + pcol;  // sA: [2][64][32]  panel stride 2048
  __bf16* dB = sB + prow * 32 + pcol;  // sB: [2][128][32] panel stride 4096
  for (int k0 = 0; k0 < K; k0 += 64) {
    __syncthreads();
    async_cp16(ga + k0,      dA);
    async_cp16(ga + k0 + 32, dA + 2048);
    async_cp16(gb + k0,      dB);
    async_cp16(gb + k0 + 32, dB + 4096);
    async_cp16(gb + (long)64 * K + k0,      dB + 64 * 32);
    async_cp16(gb + (long)64 * K + k0 + 32, dB + 4096 + 64 * 32);
    __syncthreads();
    #pragma unroll
    for (int p = 0; p < 2; ++p) {
      bf16x8 af[2], bfr[4];
      #pragma unroll
      for (int i = 0; i < 2; ++i)
        af[i]  = *(const bf16x8*)(sA + p * 2048 + (wm + i * 16 + l16) * 32 + quad * 8);
      #pragma unroll
      for (int j = 0; j < 4; ++j)
        bfr[j] = *(const bf16x8*)(sB + p * 4096 + (wn + j * 16 + l16) * 32 + quad * 8);
      #pragma unroll
      for (int i = 0; i < 2; ++i)
        #pragma unroll
        for (int j = 0; j < 4; ++j)
          acc[i][j] = __builtin_amdgcn_mfma_f32_16x16x32_bf16(af[i], bfr[j], acc[i][j], 0, 0, 0);
    }
  }
}

__global__ __launch_bounds__(256)
void fused_all(const float* __restrict__ q, const float* __restrict__ k,
               const float* __restrict__ v, const float* __restrict__ x,
               const int* __restrict__ lens,
               const float* __restrict__ Wq, const float* __restrict__ Wk,
               const float* __restrict__ Wv, const float* __restrict__ Wqf,
               const float* __restrict__ Wkf, const float* __restrict__ Wfc,
               const float* __restrict__ imp, const float* __restrict__ gamma,
               const float* __restrict__ beta,
               __bf16* __restrict__ qkvb, __bf16* __restrict__ Wb,
               __bf16* __restrict__ qfkfT, __bf16* __restrict__ vpb,
               __bf16* __restrict__ vp2T, __bf16* __restrict__ qcat,
               __bf16* __restrict__ kcat, __bf16* __restrict__ attnb,
               float* __restrict__ out2, __bf16* __restrict__ featb,
               float* __restrict__ outp, float* __restrict__ attnf,
               unsigned* __restrict__ bar)
{
  __shared__ __align__(16) char smem[24576]; // GEMM: sA 8KB + sB 16KB; feat: 22.5KB
  __bf16* sA = (__bf16*)smem;
  __bf16* sB = sA + 2 * 64 * 32;
  const int tid = threadIdx.x;
  const int wave = tid >> 6, lane = tid & 63;
  const int quad = lane >> 4, l16 = lane & 15;
  const int wm = (wave >> 1) * 32, wn = (wave & 1) * 64;

  // ================= STAGE 0: fp32->bf16 conversions + feature softmax =================
  {
    const int gtid = blockIdx.x * 256 + tid; // 0..65535
    const float* srcs[9] = {q, k, v, Wq, Wk, Wqf, Wkf, Wv, Wfc};
    __bf16* dsts[9] = {qkvb, qkvb + NE, qkvb + 2 * NE,
                       Wb, Wb + WE, Wb + 2 * WE, Wb + 3 * WE, Wb + 4 * WE, Wb + 5 * WE};
    const long ns[9] = {NE, NE, NE, WE, WE, WE, WE, WE, WE};
    #pragma unroll
    for (int a = 0; a < 9; ++a) {
      const float* s = srcs[a];
      __bf16* d = dsts[a];
      const long n4 = ns[a] >> 2;
      for (long i = gtid; i < n4; i += 65536) {
        float4 vv = *(const float4*)(s + i * 4);
        bf16x4 o;
        o[0] = (__bf16)vv.x; o[1] = (__bf16)vv.y; o[2] = (__bf16)vv.z; o[3] = (__bf16)vv.w;
        *(bf16x4*)(d + i * 4) = o;
      }
    }
    if (blockIdx.x < 128) { // feature-distance softmax, 32 rows per block
      float* xfs = (float*)smem; // 22.5 KB
      const int b = blockIdx.x >> 4;
      const int i0 = (blockIdx.x & 15) * 32;
      for (int idx = tid; idx < L_ * NF; idx += 256) {
        int j = idx / NF, f = idx - j * NF;
        xfs[idx] = x[((long)b * L_ + j) * D_ + f];
      }
      float im[NF];
      #pragma unroll
      for (int f = 0; f < NF; ++f) im[f] = imp[f];
      const int len = lens[b];
      __syncthreads();
      for (int r = 0; r < 8; ++r) {
        const int i = i0 + wave * 8 + r;
        float xi[NF];
        #pragma unroll
        for (int f = 0; f < NF; ++f) xi[f] = xfs[i * NF + f];
        float l[8];
        float m = -INFINITY;
        #pragma unroll
        for (int t = 0; t < 8; ++t) {
          int j = lane + t * 64;
          float s = 0.f;
          #pragma unroll
          for (int f = 0; f < NF; ++f) s = fmaf(fabsf(xi[f] - xfs[j * NF + f]), im[f], s);
          s = (j < len) ? s : NEGV;
          l[t] = s;
          m = fmaxf(m, s);
        }
        #pragma unroll
        for (int o = 32; o >= 1; o >>= 1) m = fmaxf(m, __shfl_xor(m, o));
        float ssum = 0.f;
        #pragma unroll
        for (int t = 0; t < 8; ++t) { l[t] = expf(l[t] - m); ssum += l[t]; }
        #pragma unroll
        for (int o = 32; o >= 1; o >>= 1) ssum += __shfl_xor(ssum, o);
        float inv = 1.0f / ssum;
        #pragma unroll
        for (int t = 0; t < 8; ++t)
          featb[((long)b * L_ + i) * L_ + lane + t * 64] = (__bf16)(l[t] * inv);
      }
    }
  }
  gbar(bar + 0);

  // ================= STAGE 1: 5 projections (1280 tiles, 5 per block) =================
  // z: 0=qp->qcat[:,:512] 1=kp->kcat[:,:512] 2=qfT 3=kfT 4=vp
  for (int t = blockIdx.x; t < 1280; t += GRID) {
    const int z = t >> 8, r = t & 255;
    const int m0 = (r >> 2) * 64, n0 = (r & 3) * 128;
    const __bf16* A = qkvb + (long)((z == 4) ? 2 : (z & 1)) * NE;
    const __bf16* Bm = Wb + (long)z * WE;
    f32x4 acc[2][4];
    #pragma unroll
    for (int i = 0; i < 2; ++i)
      #pragma unroll
      for (int j = 0; j < 4; ++j) acc[i][j] = 0.0f;
    core_nt(A, Bm, 512, m0, n0, sA, sB, acc);
    #pragma unroll
    for (int i = 0; i < 2; ++i) {
      const int mb = m0 + wm + i * 16 + quad * 4;
      #pragma unroll
      for (int j = 0; j < 4; ++j) {
        const int nn = n0 + wn + j * 16 + l16;
        f32x4 c = acc[i][j];
        if (z < 2) {
          __bf16* C = (z == 0) ? qcat : kcat;
          #pragma unroll
          for (int r2 = 0; r2 < 4; ++r2)
            C[(long)(mb + r2) * 1024 + nn] = (__bf16)c[r2];
        } else if (z == 4) {
          #pragma unroll
          for (int r2 = 0; r2 < 4; ++r2)
            vpb[(long)(mb + r2) * 512 + nn] = (__bf16)c[r2];
        } else {
          __bf16* T = qfkfT + (long)(z - 2) * NE;
          const long bb = (long)(mb >> 9) << 18;
          const int l = mb & 511;
          bf16x4 pk;
          pk[0] = (__bf16)c[0]; pk[1] = (__bf16)c[1];
          pk[2] = (__bf16)c[2]; pk[3] = (__bf16)c[3];
          *(bf16x4*)(T + bb + (long)nn * 512 + l) = pk;
        }
      }
    }
  }
  gbar(bar + 1);

  // ===== STAGE 2: qf2 -> qcat[:,512:], kf2 -> kcat[:,512:], vp2T = NT(Wfc, vp[b]) =====
  for (int t = blockIdx.x; t < 768; t += GRID) {
    const int z = t >> 5, r = t & 31;
    const int m0 = (r >> 2) * 64, n0 = (r & 3) * 128;
    const __bf16 *A, *Bm;
    __bf16* C;
    int ldc;
    if (z < 16) {
      const int b = z & 7, s = z >> 3;
      A = featb + (long)b * WE;
      Bm = qfkfT + (long)s * NE + (long)b * WE;
      C = (s ? kcat : qcat) + (long)b * CPL + 512;
      ldc = 1024;
    } else {
      const int b = z - 16;
      A = Wb + 5 * WE; // Wfc
      Bm = vpb + (long)b * WE;
      C = vp2T + (long)b * WE;
      ldc = 512;
    }
    f32x4 acc[2][4];
    #pragma unroll
    for (int i = 0; i < 2; ++i)
      #pragma unroll
      for (int j = 0; j < 4; ++j) acc[i][j] = 0.0f;
    core_nt(A, Bm, 512, m0, n0, sA, sB, acc);
    #pragma unroll
    for (int i = 0; i < 2; ++i) {
      const int mb = m0 + wm + i * 16 + quad * 4;
      #pragma unroll
      for (int j = 0; j < 4; ++j) {
        const int nn = n0 + wn + j * 16 + l16;
        f32x4 c = acc[i][j];
        #pragma unroll
        for (int r2 = 0; r2 < 4; ++r2)
          C[(long)(mb + r2) * ldc + nn] = (__bf16)c[r2];
      }
    }
  }
  gbar(bar + 2);

  // ================= STAGE 3: scores (256 tiles, K=1024) =================
  {
    const int b = blockIdx.x >> 5, r = blockIdx.x & 31;
    const int m0 = (r >> 2) * 64, n0 = (r & 3) * 128;
    const int len = lens[b];
    const long off = (long)b * WE;
    f32x4 acc[2][4];
    #pragma unroll
    for (int i = 0; i < 2; ++i)
      #pragma unroll
      for (int j = 0; j < 4; ++j) acc[i][j] = 0.0f;
    core_nt(qcat + (long)b * CPL, kcat + (long)b * CPL, 1024, m0, n0, sA, sB, acc);
    #pragma unroll
    for (int i = 0; i < 2; ++i) {
      const int mb = m0 + wm + i * 16 + quad * 4;
      #pragma unroll
      for (int j = 0; j < 4; ++j) {
        const int nn = n0 + wn + j * 16 + l16;
        f32x4 c = acc[i][j];
        #pragma unroll
        for (int r2 = 0; r2 < 4; ++r2) {
          float vv = c[r2] * INV_TEMP;
          vv = (nn < len) ? tanhf(vv) : 0.0f;
          attnf[off + (long)(mb + r2) * 512 + nn] = vv;
          attnb[off + (long)(mb + r2) * 512 + nn] = (__bf16)vv;
        }
      }
    }
  }
  gbar(bar + 3);

  // ================= STAGE 4: out2 = attn @ vp2 (256 tiles) =================
  {
    const int b = blockIdx.x >> 5, r = blockIdx.x & 31;
    const int m0 = (r >> 2) * 64, n0 = (r & 3) * 128;
    const long off = (long)b * WE;
    f32x4 acc[2][4];
    #pragma unroll
    for (int i = 0; i < 2; ++i)
      #pragma unroll
      for (int j = 0; j < 4; ++j) acc[i][j] = 0.0f;
    core_nt(attnb + (long)b * WE, vp2T + (long)b * WE, 512, m0, n0, sA, sB, acc);
    #pragma unroll
    for (int i = 0; i < 2; ++i) {
      const int mb = m0 + wm + i * 16 + quad * 4;
      #pragma unroll
      for (int j = 0; j < 4; ++j) {
        const int nn = n0 + wn + j * 16 + l16;
        f32x4 c = acc[i][j];
        #pragma unroll
        for (int r2 = 0; r2 < 4; ++r2)
          out2[off + (long)(mb + r2) * 512 + nn] = c[r2];
      }
    }
  }
  gbar(bar + 4);

  // ================= STAGE 5: LayerNorm(out2 + q) =================
  for (int r = 0; r < 4; ++r) {
    const long row = (long)blockIdx.x * 16 + wave * 4 + r;
    float vv[8];
    float s = 0.f, ss = 0.f;
    #pragma unroll
    for (int t = 0; t < 8; ++t) {
      float u = out2[row * D_ + lane + t * 64] + q[row * D_ + lane + t * 64];
      vv[t] = u; s += u; ss = fmaf(u, u, ss);
    }
    #pragma unroll
    for (int o = 32; o >= 1; o >>= 1) { s += __shfl_xor(s, o); ss += __shfl_xor(ss, o); }
    const float mu = s * (1.0f / D_);
    const float var = ss * (1.0f / D_) - mu * mu;
    const float inv = 1.0f / sqrtf(var + 1e-6f);
    #pragma unroll
    for (int t = 0; t < 8; ++t) {
      int d = lane + t * 64;
      outp[row * D_ + d] = (vv[t] - mu) * inv * gamma[d] + beta[d];
    }
  }
}

extern "C" void kernel_launch(void* const* d_in, const int* in_sizes, int n_in,
                              void* d_out, int out_size, void* d_ws, size_t ws_size,
                              hipStream_t stream) {
    const float* q     = (const float*)d_in[0];
    const float* k     = (const float*)d_in[1];
    const float* v     = (const float*)d_in[2];
    const float* x     = (const float*)d_in[3];
    const int*   lens  = (const int*)d_in[4];
    const float* Wq    = (const float*)d_in[5];
    const float* Wk    = (const float*)d_in[6];
    const float* Wv    = (const float*)d_in[7];
    const float* Wqf   = (const float*)d_in[8];
    const float* Wkf   = (const float*)d_in[9];
    const float* Wfc   = (const float*)d_in[10];
    const float* imp   = (const float*)d_in[11];
    const float* gamma = (const float*)d_in[12];
    const float* beta  = (const float*)d_in[13];

    constexpr long MB = 1 << 20;
    char* w = (char*)d_ws;
    __bf16* qkvb  = (__bf16*)(w);            //  0..12MB : q,k,v bf16
    __bf16* Wb    = (__bf16*)(w + 12 * MB);  // 12..15MB : Wq,Wk,Wqf,Wkf,Wv,Wfc
    __bf16* qfkfT = (__bf16*)(w + 15 * MB);  // 15..23MB : qfT,kfT
    __bf16* vpb   = (__bf16*)(w + 23 * MB);  // 23..27MB : vp
    __bf16* vp2T  = (__bf16*)(w + 27 * MB);  // 27..31MB : vp2T
    __bf16* qcat  = (__bf16*)(w + 31 * MB);  // 31..39MB : [qp | qf2] K=1024
    __bf16* kcat  = (__bf16*)(w + 39 * MB);  // 39..47MB : [kp | kf2]
    __bf16* attnb = (__bf16*)(w + 47 * MB);  // 47..51MB : attn bf16
    float*  out2  = (float*)(w + 51 * MB);   // 51..59MB : pre-LN fp32
    __bf16* featb = (__bf16*)(w + 59 * MB);  // 59..63MB : feat_attn bf16
    unsigned* bar = (unsigned*)(w + 63 * MB); // 63MB    : 5 barrier counters

    float*  outp  = (float*)d_out;           // output 0 [B,L,D]
    float*  attnf = outp + NE;               // output 1 [B,L,L]

    hipMemsetAsync(bar, 0, 512, stream);     // zero barrier counters (captured in graph)

    fused_all<<<GRID, 256, 0, stream>>>(q, k, v, x, lens, Wq, Wk, Wv, Wqf, Wkf, Wfc,
                                        imp, gamma, beta,
                                        qkvb, Wb, qfkfT, vpb, vp2T, qcat, kcat,
                                        attnb, out2, featb, outp, attnf, bar);
}

// Round 7
// 204.883 us; speedup vs baseline: 2.1053x; 2.1053x over previous
//
#include <hip/hip_runtime.h>
#include <math.h>

typedef __bf16 bf16x8 __attribute__((ext_vector_type(8)));
typedef __bf16 bf16x4 __attribute__((ext_vector_type(4)));
typedef float  f32x4  __attribute__((ext_vector_type(4)));

namespace {
constexpr int L_ = 512, D_ = 512, NF = 11;
constexpr long WE = (long)L_ * L_;   // 262144 elems, one 512x512 plane
constexpr long NE = 8 * WE;          // 2097152 elems, B*L*D
constexpr long CPL = 512L * 1024;    // concatenated plane (512 rows x 1024)
constexpr float NEGV = -1.0e9f;
constexpr float INV_TEMP = 0.044194173824159216f; // 1/sqrt(512)
}

typedef __attribute__((address_space(1))) void gv_t;
typedef __attribute__((address_space(3))) void lv_t;

__device__ __forceinline__ void async_cp16(const void* g, void* l) {
  __builtin_amdgcn_global_load_lds((gv_t*)g, (lv_t*)l, 16, 0, 0);
}

__device__ __forceinline__ bf16x8 cvt8(const float* p) {
  float4 a0 = *(const float4*)(p);
  float4 a1 = *(const float4*)(p + 4);
  bf16x8 f;
  f[0] = (__bf16)a0.x; f[1] = (__bf16)a0.y; f[2] = (__bf16)a0.z; f[3] = (__bf16)a0.w;
  f[4] = (__bf16)a1.x; f[5] = (__bf16)a1.y; f[6] = (__bf16)a1.z; f[7] = (__bf16)a1.w;
  return f;
}

// ======== featcvt: y=0 weight fp32->bf16 (6 mats), y=1 feature softmax ========
__global__ __launch_bounds__(256)
void featcvt_kernel(const float* __restrict__ Wq, const float* __restrict__ Wk,
                    const float* __restrict__ Wqf, const float* __restrict__ Wkf,
                    const float* __restrict__ Wv, const float* __restrict__ Wfc,
                    __bf16* __restrict__ Wb,
                    const float* __restrict__ x, const float* __restrict__ imp,
                    const int* __restrict__ lens, __bf16* __restrict__ featb)
{
  __shared__ float xfs[L_ * NF]; // 22.5 KB (feat path)
  const int tid = threadIdx.x;
  const int wave = tid >> 6, lane = tid & 63;
  if (blockIdx.y == 0) {
    const float* srcs[6] = {Wq, Wk, Wqf, Wkf, Wv, Wfc};
    const int gtid = blockIdx.x * 256 + tid; // 0..32767
    #pragma unroll
    for (int a = 0; a < 6; ++a) {
      const float* s = srcs[a];
      __bf16* d = Wb + (long)a * WE;
      #pragma unroll
      for (int r = 0; r < 2; ++r) {
        long i = (long)(gtid + r * 32768) * 4;
        float4 vv = *(const float4*)(s + i);
        bf16x4 o;
        o[0] = (__bf16)vv.x; o[1] = (__bf16)vv.y; o[2] = (__bf16)vv.z; o[3] = (__bf16)vv.w;
        *(bf16x4*)(d + i) = o;
      }
    }
  } else {
    const int b = blockIdx.x >> 4;
    const int i0 = (blockIdx.x & 15) * 32;
    for (int idx = tid; idx < L_ * NF; idx += 256) {
      int j = idx / NF, f = idx - j * NF;
      xfs[idx] = x[((long)b * L_ + j) * D_ + f];
    }
    float im[NF];
    #pragma unroll
    for (int f = 0; f < NF; ++f) im[f] = imp[f];
    const int len = lens[b];
    __syncthreads();
    for (int r = 0; r < 8; ++r) {
      const int i = i0 + wave * 8 + r;
      float xi[NF];
      #pragma unroll
      for (int f = 0; f < NF; ++f) xi[f] = xfs[i * NF + f];
      float l[8];
      float m = -INFINITY;
      #pragma unroll
      for (int t = 0; t < 8; ++t) {
        int j = lane + t * 64;
        float s = 0.f;
        #pragma unroll
        for (int f = 0; f < NF; ++f) s = fmaf(fabsf(xi[f] - xfs[j * NF + f]), im[f], s);
        s = (j < len) ? s : NEGV;
        l[t] = s;
        m = fmaxf(m, s);
      }
      #pragma unroll
      for (int o = 32; o >= 1; o >>= 1) m = fmaxf(m, __shfl_xor(m, o));
      float ssum = 0.f;
      #pragma unroll
      for (int t = 0; t < 8; ++t) { l[t] = expf(l[t] - m); ssum += l[t]; }
      #pragma unroll
      for (int o = 32; o >= 1; o >>= 1) ssum += __shfl_xor(ssum, o);
      float inv = 1.0f / ssum;
      #pragma unroll
      for (int t = 0; t < 8; ++t)
        featb[((long)b * L_ + i) * L_ + lane + t * 64] = (__bf16)(l[t] * inv);
    }
  }
}

// ======== proj: A fp32 direct-to-register, B bf16 weights via LDS ========
// 128x128 tile, BK=32. Wave tiles 32x128 (wm = wave*32, full N per wave).
// z: 0=qp->qcat[:,:512] 1=kp->kcat[:,:512] 2=qfT 3=kfT 4=vp
__global__ __launch_bounds__(256)
void proj_kernel(const float* __restrict__ q, const float* __restrict__ k,
                 const float* __restrict__ v, const __bf16* __restrict__ Wb,
                 __bf16* __restrict__ qcat, __bf16* __restrict__ kcat,
                 __bf16* __restrict__ qfkfT, __bf16* __restrict__ vpb)
{
  __shared__ __align__(16) __bf16 sB[128 * 32]; // 8 KB
  const int z = blockIdx.z;
  const float* As[5] = {q, k, q, k, v};
  const float* A = As[z];
  const __bf16* Bw = Wb + (long)z * WE;
  const int tid = threadIdx.x;
  const int wave = tid >> 6, lane = tid & 63;
  const int quad = lane >> 4, l16 = lane & 15;
  const int m0 = blockIdx.y * 128, n0 = blockIdx.x * 128;
  // B staging: 2 chunks/thread
  const int brow = tid >> 2, bcol = (tid & 3) * 8;
  const __bf16* gb = Bw + (long)(n0 + brow) * 512 + bcol;
  __bf16* dB = sB + brow * 32 + bcol;

  f32x4 acc[2][8];
  #pragma unroll
  for (int i = 0; i < 2; ++i)
    #pragma unroll
    for (int j = 0; j < 8; ++j) acc[i][j] = 0.0f;

  const float* ga0 = A + (long)(m0 + wave * 32 + l16) * 512 + quad * 8;
  const float* ga1 = ga0 + 16 * 512;

  for (int k0 = 0; k0 < 512; k0 += 32) {
    __syncthreads();
    async_cp16(gb + k0,            dB);
    async_cp16(gb + 64 * 512 + k0, dB + 64 * 32);
    // A fragments: pure VGPR path, hoistable across barriers
    bf16x8 af[2];
    af[0] = cvt8(ga0 + k0);
    af[1] = cvt8(ga1 + k0);
    __syncthreads();
    bf16x8 bfr[8];
    #pragma unroll
    for (int j = 0; j < 8; ++j)
      bfr[j] = *(const bf16x8*)(sB + (j * 16 + l16) * 32 + quad * 8);
    #pragma unroll
    for (int i = 0; i < 2; ++i)
      #pragma unroll
      for (int j = 0; j < 8; ++j)
        acc[i][j] = __builtin_amdgcn_mfma_f32_16x16x32_bf16(af[i], bfr[j], acc[i][j], 0, 0, 0);
  }

  // epilogue: C/D col = lane&15, row = quad*4 + reg
  #pragma unroll
  for (int i = 0; i < 2; ++i) {
    const int mb = m0 + wave * 32 + i * 16 + quad * 4;
    #pragma unroll
    for (int j = 0; j < 8; ++j) {
      const int nn = n0 + j * 16 + l16;
      f32x4 c = acc[i][j];
      if (z < 2) {
        __bf16* C = (z == 0) ? qcat : kcat;
        #pragma unroll
        for (int r2 = 0; r2 < 4; ++r2)
          C[(long)(mb + r2) * 1024 + nn] = (__bf16)c[r2];
      } else if (z == 4) {
        #pragma unroll
        for (int r2 = 0; r2 < 4; ++r2)
          vpb[(long)(mb + r2) * 512 + nn] = (__bf16)c[r2];
      } else {
        __bf16* T = qfkfT + (long)(z - 2) * NE;
        const long bb = (long)(mb >> 9) << 18;
        const int l = mb & 511;
        bf16x4 pk;
        pk[0] = (__bf16)c[0]; pk[1] = (__bf16)c[1];
        pk[2] = (__bf16)c[2]; pk[3] = (__bf16)c[3];
        *(bf16x4*)(T + bb + (long)nn * 512 + l) = pk;
      }
    }
  }
}

// ================= 64x128 batched NT core, BK=64 panels (R5) =================
__device__ __forceinline__ void core_64x128(const __bf16* __restrict__ A,
                                            const __bf16* __restrict__ B, int K,
                                            __bf16* sA, __bf16* sB, f32x4 (&acc)[2][4])
{
  const int tid = threadIdx.x;
  const int wave = tid >> 6, lane = tid & 63;
  const int m0 = blockIdx.y * 64, n0 = blockIdx.x * 128;
  const int prow = wave * 16 + (lane >> 2), pcol = (lane & 3) * 8;
  const int quad = lane >> 4, l16 = lane & 15;
  const int wm = (wave >> 1) * 32, wn = (wave & 1) * 64;
  const __bf16* ga = A + (long)(m0 + prow) * K + pcol;
  const __bf16* gb = B + (long)(n0 + prow) * K + pcol;
  __bf16* dA = sA + prow * 32 + pcol;  // sA: [2][64][32]  panel stride 2048
  __bf16* dB = sB + prow * 32 + pcol;  // sB: [2][128][32] panel stride 4096
  for (int k0 = 0; k0 < K; k0 += 64) {
    __syncthreads();
    async_cp16(ga + k0,      dA);
    async_cp16(ga + k0 + 32, dA + 2048);
    async_cp16(gb + k0,      dB);
    async_cp16(gb + k0 + 32, dB + 4096);
    async_cp16(gb + (long)64 * K + k0,      dB + 64 * 32);
    async_cp16(gb + (long)64 * K + k0 + 32, dB + 4096 + 64 * 32);
    __syncthreads();
    #pragma unroll
    for (int p = 0; p < 2; ++p) {
      bf16x8 af[2], bfr[4];
      #pragma unroll
      for (int i = 0; i < 2; ++i)
        af[i]  = *(const bf16x8*)(sA + p * 2048 + (wm + i * 16 + l16) * 32 + quad * 8);
      #pragma unroll
      for (int j = 0; j < 4; ++j)
        bfr[j] = *(const bf16x8*)(sB + p * 4096 + (wn + j * 16 + l16) * 32 + quad * 8);
      #pragma unroll
      for (int i = 0; i < 2; ++i)
        #pragma unroll
        for (int j = 0; j < 4; ++j)
          acc[i][j] = __builtin_amdgcn_mfma_f32_16x16x32_bf16(af[i], bfr[j], acc[i][j], 0, 0, 0);
    }
  }
}

// ================= 64x64 batched NT core, BK=64 panels (R5) =================
__device__ __forceinline__ void core_64x64(const __bf16* __restrict__ A,
                                           const __bf16* __restrict__ B, int K,
                                           __bf16* sA, __bf16* sB, f32x4 (&acc)[2][2])
{
  const int tid = threadIdx.x;
  const int wave = tid >> 6, lane = tid & 63;
  const int m0 = blockIdx.y * 64, n0 = blockIdx.x * 64;
  const int prow = wave * 16 + (lane >> 2), pcol = (lane & 3) * 8;
  const int quad = lane >> 4, l16 = lane & 15;
  const int wm = (wave >> 1) * 32, wn = (wave & 1) * 32;
  const __bf16* ga = A + (long)(m0 + prow) * K + pcol;
  const __bf16* gb = B + (long)(n0 + prow) * K + pcol;
  __bf16* dA = sA + prow * 32 + pcol;
  __bf16* dB = sB + prow * 32 + pcol;
  for (int k0 = 0; k0 < K; k0 += 64) {
    __syncthreads();
    async_cp16(ga + k0,      dA);
    async_cp16(ga + k0 + 32, dA + 2048);
    async_cp16(gb + k0,      dB);
    async_cp16(gb + k0 + 32, dB + 2048);
    __syncthreads();
    #pragma unroll
    for (int p = 0; p < 2; ++p) {
      bf16x8 af[2], bfr[2];
      #pragma unroll
      for (int i = 0; i < 2; ++i)
        af[i]  = *(const bf16x8*)(sA + p * 2048 + (wm + i * 16 + l16) * 32 + quad * 8);
      #pragma unroll
      for (int j = 0; j < 2; ++j)
        bfr[j] = *(const bf16x8*)(sB + p * 2048 + (wn + j * 16 + l16) * 32 + quad * 8);
      #pragma unroll
      for (int i = 0; i < 2; ++i)
        #pragma unroll
        for (int j = 0; j < 2; ++j)
          acc[i][j] = __builtin_amdgcn_mfma_f32_16x16x32_bf16(af[i], bfr[j], acc[i][j], 0, 0, 0);
    }
  }
}

// mega2: z 0..7 qf2 -> qcat[:,512:], z 8..15 kf2 -> kcat[:,512:], z 16..23 vp2T = NT(Wfc, vp[b])
__global__ __launch_bounds__(256)
void mega2_kernel(const __bf16* __restrict__ featb, const __bf16* __restrict__ qfkfT,
                  const __bf16* __restrict__ Wfcb, const __bf16* __restrict__ vpb,
                  __bf16* __restrict__ qcat, __bf16* __restrict__ kcat,
                  __bf16* __restrict__ vp2T)
{
  __shared__ __align__(16) __bf16 sA[2 * 64 * 32];
  __shared__ __align__(16) __bf16 sB[2 * 128 * 32];
  const int z = blockIdx.z;
  const __bf16 *A, *B;
  __bf16* C;
  int ldc;
  if (z < 16) {
    const int b = z & 7, s = z >> 3;
    A = featb + (long)b * WE;
    B = qfkfT + (long)s * NE + (long)b * WE;
    C = (s ? kcat : qcat) + (long)b * CPL + 512;
    ldc = 1024;
  } else {
    const int b = z - 16;
    A = Wfcb;
    B = vpb + (long)b * WE;
    C = vp2T + (long)b * WE;
    ldc = 512;
  }
  f32x4 acc[2][4];
  #pragma unroll
  for (int i = 0; i < 2; ++i)
    #pragma unroll
    for (int j = 0; j < 4; ++j) acc[i][j] = 0.0f;
  core_64x128(A, B, 512, sA, sB, acc);

  const int wave = threadIdx.x >> 6, lane = threadIdx.x & 63;
  const int quad = lane >> 4, l16 = lane & 15;
  const int wm = (wave >> 1) * 32, wn = (wave & 1) * 64;
  #pragma unroll
  for (int i = 0; i < 2; ++i) {
    const int mb = blockIdx.y * 64 + wm + i * 16 + quad * 4;
    #pragma unroll
    for (int j = 0; j < 4; ++j) {
      const int nn = blockIdx.x * 128 + wn + j * 16 + l16;
      f32x4 c = acc[i][j];
      #pragma unroll
      for (int r2 = 0; r2 < 4; ++r2)
        C[(long)(mb + r2) * ldc + nn] = (__bf16)c[r2];
    }
  }
}

// scores: attn = tanh(mask((qcat . kcat^T)/temp)), K=1024, fp32 out only
__global__ __launch_bounds__(256)
void scores_kernel(const __bf16* __restrict__ qcat, const __bf16* __restrict__ kcat,
                   const int* __restrict__ lens, float* __restrict__ attnf)
{
  __shared__ __align__(16) __bf16 sA[2 * 64 * 32];
  __shared__ __align__(16) __bf16 sB[2 * 64 * 32];
  const int b = blockIdx.z;
  const int len = lens[b];
  f32x4 acc[2][2];
  #pragma unroll
  for (int i = 0; i < 2; ++i)
    #pragma unroll
    for (int j = 0; j < 2; ++j) acc[i][j] = 0.0f;
  core_64x64(qcat + (long)b * CPL, kcat + (long)b * CPL, 1024, sA, sB, acc);

  const long off = (long)b * WE;
  const int wave = threadIdx.x >> 6, lane = threadIdx.x & 63;
  const int quad = lane >> 4, l16 = lane & 15;
  const int wm = (wave >> 1) * 32, wn = (wave & 1) * 32;
  #pragma unroll
  for (int i = 0; i < 2; ++i) {
    const int mb = blockIdx.y * 64 + wm + i * 16 + quad * 4;
    #pragma unroll
    for (int j = 0; j < 2; ++j) {
      const int nn = blockIdx.x * 64 + wn + j * 16 + l16;
      f32x4 c = acc[i][j];
      #pragma unroll
      for (int r2 = 0; r2 < 4; ++r2) {
        float vv = c[r2] * INV_TEMP;
        vv = (nn < len) ? tanhf(vv) : 0.0f;
        attnf[off + (long)(mb + r2) * 512 + nn] = vv;
      }
    }
  }
}

// av2: out2[b] = attn[b] @ vp2[b]; A = attn fp32 direct-to-register, B = vp2T bf16 via LDS
// 64x64 tile, BK=32, wave tiles 16x64.
__global__ __launch_bounds__(256)
void av2_kernel(const float* __restrict__ attnf, const __bf16* __restrict__ vp2T,
                float* __restrict__ out2)
{
  __shared__ __align__(16) __bf16 sB[64 * 32]; // 4 KB
  const int b = blockIdx.z;
  const float* A = attnf + (long)b * WE;
  const __bf16* B = vp2T + (long)b * WE;
  const int tid = threadIdx.x;
  const int wave = tid >> 6, lane = tid & 63;
  const int quad = lane >> 4, l16 = lane & 15;
  const int m0 = blockIdx.y * 64, n0 = blockIdx.x * 64;
  const int brow = tid >> 2, bcol = (tid & 3) * 8;
  const __bf16* gb = B + (long)(n0 + brow) * 512 + bcol;
  __bf16* dB = sB + brow * 32 + bcol;

  f32x4 acc[4];
  #pragma unroll
  for (int j = 0; j < 4; ++j) acc[j] = 0.0f;

  const float* ga = A + (long)(m0 + wave * 16 + l16) * 512 + quad * 8;

  for (int k0 = 0; k0 < 512; k0 += 32) {
    __syncthreads();
    async_cp16(gb + k0, dB);
    bf16x8 af = cvt8(ga + k0);   // VGPR path, hoistable
    __syncthreads();
    #pragma unroll
    for (int j = 0; j < 4; ++j) {
      bf16x8 bfr = *(const bf16x8*)(sB + (j * 16 + l16) * 32 + quad * 8);
      acc[j] = __builtin_amdgcn_mfma_f32_16x16x32_bf16(af, bfr, acc[j], 0, 0, 0);
    }
  }

  const long off = (long)b * WE;
  const int mb = m0 + wave * 16 + quad * 4;
  #pragma unroll
  for (int j = 0; j < 4; ++j) {
    const int nn = n0 + j * 16 + l16;
    f32x4 c = acc[j];
    #pragma unroll
    for (int r2 = 0; r2 < 4; ++r2)
      out2[off + (long)(mb + r2) * 512 + nn] = c[r2];
  }
}

// ---------------- LayerNorm: 4 rows per block ----------------
__global__ __launch_bounds__(256) void ln_kernel(const float* __restrict__ xin, const float* __restrict__ res,
                                                 const float* __restrict__ gamma, const float* __restrict__ beta,
                                                 float* __restrict__ out)
{
    const int wave = threadIdx.x >> 6, lane = threadIdx.x & 63;
    const long row = blockIdx.x * 4 + wave;
    float v[8];
    float s = 0.f, ss = 0.f;
    #pragma unroll
    for (int t = 0; t < 8; ++t) {
        float u = xin[row * D_ + lane + t * 64] + res[row * D_ + lane + t * 64];
        v[t] = u; s += u; ss = fmaf(u, u, ss);
    }
    #pragma unroll
    for (int o = 32; o >= 1; o >>= 1) { s += __shfl_xor(s, o); ss += __shfl_xor(ss, o); }
    const float mu = s * (1.0f / D_);
    const float var = ss * (1.0f / D_) - mu * mu;
    const float inv = 1.0f / sqrtf(var + 1e-6f);
    #pragma unroll
    for (int t = 0; t < 8; ++t) {
        int d = lane + t * 64;
        out[row * D_ + d] = (v[t] - mu) * inv * gamma[d] + beta[d];
    }
}

extern "C" void kernel_launch(void* const* d_in, const int* in_sizes, int n_in,
                              void* d_out, int out_size, void* d_ws, size_t ws_size,
                              hipStream_t stream) {
    const float* q     = (const float*)d_in[0];
    const float* k     = (const float*)d_in[1];
    const float* v     = (const float*)d_in[2];
    const float* x     = (const float*)d_in[3];
    const int*   lens  = (const int*)d_in[4];
    const float* Wq    = (const float*)d_in[5];
    const float* Wk    = (const float*)d_in[6];
    const float* Wv    = (const float*)d_in[7];
    const float* Wqf   = (const float*)d_in[8];
    const float* Wkf   = (const float*)d_in[9];
    const float* Wfc   = (const float*)d_in[10];
    const float* imp   = (const float*)d_in[11];
    const float* gamma = (const float*)d_in[12];
    const float* beta  = (const float*)d_in[13];

    constexpr long MB = 1 << 20;
    char* w = (char*)d_ws;
    __bf16* Wb    = (__bf16*)(w);            //  0.. 3MB : Wq,Wk,Wqf,Wkf,Wv,Wfc bf16
    __bf16* qfkfT = (__bf16*)(w + 3 * MB);   //  3..11MB : qfT,kfT
    __bf16* vpb   = (__bf16*)(w + 11 * MB);  // 11..15MB : vp
    __bf16* vp2T  = (__bf16*)(w + 15 * MB);  // 15..19MB : vp2T
    __bf16* qcat  = (__bf16*)(w + 19 * MB);  // 19..27MB : [qp | qf2] K=1024
    __bf16* kcat  = (__bf16*)(w + 27 * MB);  // 27..35MB : [kp | kf2]
    float*  out2  = (float*)(w + 35 * MB);   // 35..43MB : pre-LN fp32
    __bf16* featb = (__bf16*)(w + 43 * MB);  // 43..47MB : feat_attn bf16

    float*  outp  = (float*)d_out;           // output 0 [B,L,D]
    float*  attnf = outp + NE;               // output 1 [B,L,L]

    // 1) weight cvt (y=0) + feature softmax (y=1)
    featcvt_kernel<<<dim3(128, 2), 256, 0, stream>>>(Wq, Wk, Wqf, Wkf, Wv, Wfc, Wb,
                                                     x, imp, lens, featb);

    // 2) 5 projections, A fp32 direct (640 blocks)
    proj_kernel<<<dim3(4, 32, 5), 256, 0, stream>>>(q, k, v, Wb, qcat, kcat, qfkfT, vpb);

    // 3) qf2,kf2 -> cat right halves + vp2T = Wfc.vp^T (768 blocks)
    mega2_kernel<<<dim3(4, 8, 24), 256, 0, stream>>>(featb, qfkfT, Wb + 5 * WE, vpb,
                                                     qcat, kcat, vp2T);

    // 4) attn = tanh(mask(qcat.kcat^T / temp)), K=1024 (512 blocks)
    scores_kernel<<<dim3(8, 8, 8), 256, 0, stream>>>(qcat, kcat, lens, attnf);

    // 5) out2 = attn @ vp2, A fp32 direct (512 blocks)
    av2_kernel<<<dim3(8, 8, 8), 256, 0, stream>>>(attnf, vp2T, out2);

    // 6) LayerNorm(out2 + q)
    ln_kernel<<<1024, 256, 0, stream>>>(out2, q, gamma, beta, outp);
}

// Round 8
// 185.722 us; speedup vs baseline: 2.3226x; 1.1032x over previous
//
#include <hip/hip_runtime.h>
#include <math.h>

typedef __bf16 bf16x8 __attribute__((ext_vector_type(8)));
typedef __bf16 bf16x4 __attribute__((ext_vector_type(4)));
typedef float  f32x4  __attribute__((ext_vector_type(4)));

namespace {
constexpr int L_ = 512, D_ = 512, NF = 11;
constexpr long WE = (long)L_ * L_;   // 262144 elems, one 512x512 plane
constexpr long NE = 8 * WE;          // 2097152 elems, B*L*D
constexpr long CPL = 512L * 1024;    // concatenated plane (512 rows x 1024)
constexpr float NEGV = -1.0e9f;
constexpr float INV_TEMP = 0.044194173824159216f; // 1/sqrt(512)
}

__device__ __forceinline__ bf16x8 cvt2(float4 a0, float4 a1) {
  bf16x8 f;
  f[0] = (__bf16)a0.x; f[1] = (__bf16)a0.y; f[2] = (__bf16)a0.z; f[3] = (__bf16)a0.w;
  f[4] = (__bf16)a1.x; f[5] = (__bf16)a1.y; f[6] = (__bf16)a1.z; f[7] = (__bf16)a1.w;
  return f;
}

// ======== 64x128 NT core, BK=64 (two 32-col panels), VGPR-prefetch staging ========
// Pipeline: [barrier; ds_write staged regs (vmcnt waits HERE, post-compute);
//            barrier; issue next tile's global loads; ds_read+MFMA]  — the load
// latency window spans the whole compute section instead of being drained at issue.
// A is fp32 (AF32=true, converted in-register before ds_write) or bf16.
template<bool AF32>
__device__ __forceinline__ void core_vdb(const void* Av, const __bf16* __restrict__ B,
                                         int K, int m0, int n0,
                                         __bf16* sA, __bf16* sB, f32x4 (&acc)[2][4])
{
  const int tid = threadIdx.x;
  const int wave = tid >> 6, lane = tid & 63;
  const int srow = tid >> 2, scol = (tid & 3) * 8;
  const int quad = lane >> 4, l16 = lane & 15;
  const int wm = (wave >> 1) * 32, wn = (wave & 1) * 64;
  const __bf16* gB  = B + (long)(n0 + srow) * K + scol;
  const float*  gAf = (const float*)Av  + (long)(m0 + srow) * K + scol;
  const __bf16* gAb = (const __bf16*)Av + (long)(m0 + srow) * K + scol;
  __bf16* dA = sA + srow * 32 + scol;   // sA: [2][64][32]  panel stride 2048
  __bf16* dB = sB + srow * 32 + scol;   // sB: [2][128][32] panel stride 4096

  float4 fa[2][2];
  bf16x8 ba[2];
  bf16x8 rb[4];

  // tile-0 prefetch
  {
    if (AF32) {
      fa[0][0] = *(const float4*)(gAf);      fa[0][1] = *(const float4*)(gAf + 4);
      fa[1][0] = *(const float4*)(gAf + 32); fa[1][1] = *(const float4*)(gAf + 36);
    } else {
      ba[0] = *(const bf16x8*)(gAb);
      ba[1] = *(const bf16x8*)(gAb + 32);
    }
    rb[0] = *(const bf16x8*)(gB);
    rb[1] = *(const bf16x8*)(gB + 32);
    rb[2] = *(const bf16x8*)(gB + (long)64 * K);
    rb[3] = *(const bf16x8*)(gB + (long)64 * K + 32);
  }

  for (int k0 = 0; k0 < K; k0 += 64) {
    __syncthreads();                 // all waves done reading previous LDS tile
    bf16x8 wa0, wa1;
    if (AF32) { wa0 = cvt2(fa[0][0], fa[0][1]); wa1 = cvt2(fa[1][0], fa[1][1]); }
    else      { wa0 = ba[0]; wa1 = ba[1]; }
    *(bf16x8*)(dA)                  = wa0;      // panel 0
    *(bf16x8*)(dA + 2048)           = wa1;      // panel 1
    *(bf16x8*)(dB)                  = rb[0];
    *(bf16x8*)(dB + 4096)           = rb[1];
    *(bf16x8*)(dB + 64 * 32)        = rb[2];
    *(bf16x8*)(dB + 4096 + 64 * 32) = rb[3];
    __syncthreads();                 // writes visible (lgkm drain, fast)
    if (k0 + 64 < K) {               // issue next tile early; waits land next iter
      const int kn = k0 + 64;
      if (AF32) {
        fa[0][0] = *(const float4*)(gAf + kn);      fa[0][1] = *(const float4*)(gAf + kn + 4);
        fa[1][0] = *(const float4*)(gAf + kn + 32); fa[1][1] = *(const float4*)(gAf + kn + 36);
      } else {
        ba[0] = *(const bf16x8*)(gAb + kn);
        ba[1] = *(const bf16x8*)(gAb + kn + 32);
      }
      rb[0] = *(const bf16x8*)(gB + kn);
      rb[1] = *(const bf16x8*)(gB + kn + 32);
      rb[2] = *(const bf16x8*)(gB + (long)64 * K + kn);
      rb[3] = *(const bf16x8*)(gB + (long)64 * K + kn + 32);
    }
    #pragma unroll
    for (int p = 0; p < 2; ++p) {
      bf16x8 af[2], bfr[4];
      #pragma unroll
      for (int i = 0; i < 2; ++i)
        af[i]  = *(const bf16x8*)(sA + p * 2048 + (wm + i * 16 + l16) * 32 + quad * 8);
      #pragma unroll
      for (int j = 0; j < 4; ++j)
        bfr[j] = *(const bf16x8*)(sB + p * 4096 + (wn + j * 16 + l16) * 32 + quad * 8);
      #pragma unroll
      for (int i = 0; i < 2; ++i)
        #pragma unroll
        for (int j = 0; j < 4; ++j)
          acc[i][j] = __builtin_amdgcn_mfma_f32_16x16x32_bf16(af[i], bfr[j], acc[i][j], 0, 0, 0);
    }
  }
}

// ======== proj: A = q/k/v fp32 direct, B = bf16 weights. grid (4,64,5) ========
// z: 0=qp->qcat[:,:512] 1=kp->kcat[:,:512] 2=qfT 3=kfT 4=vp
__global__ __launch_bounds__(256)
void proj_kernel(const float* __restrict__ q, const float* __restrict__ k,
                 const float* __restrict__ v, const __bf16* __restrict__ Wb,
                 __bf16* __restrict__ qcat, __bf16* __restrict__ kcat,
                 __bf16* __restrict__ qfkfT, __bf16* __restrict__ vpb)
{
  __shared__ __align__(16) __bf16 sA[2 * 64 * 32];
  __shared__ __align__(16) __bf16 sB[2 * 128 * 32];
  const int z = blockIdx.z;
  const float* As[5] = {q, k, q, k, v};
  const int m0 = blockIdx.y * 64, n0 = blockIdx.x * 128;
  f32x4 acc[2][4];
  #pragma unroll
  for (int i = 0; i < 2; ++i)
    #pragma unroll
    for (int j = 0; j < 4; ++j) acc[i][j] = 0.0f;
  core_vdb<true>(As[z], Wb + (long)z * WE, 512, m0, n0, sA, sB, acc);

  const int wave = threadIdx.x >> 6, lane = threadIdx.x & 63;
  const int quad = lane >> 4, l16 = lane & 15;
  const int wm = (wave >> 1) * 32, wn = (wave & 1) * 64;
  #pragma unroll
  for (int i = 0; i < 2; ++i) {
    const int mb = m0 + wm + i * 16 + quad * 4;
    #pragma unroll
    for (int j = 0; j < 4; ++j) {
      const int nn = n0 + wn + j * 16 + l16;
      f32x4 c = acc[i][j];
      if (z < 2) {
        __bf16* C = (z == 0) ? qcat : kcat;
        #pragma unroll
        for (int r2 = 0; r2 < 4; ++r2)
          C[(long)(mb + r2) * 1024 + nn] = (__bf16)c[r2];
      } else if (z == 4) {
        #pragma unroll
        for (int r2 = 0; r2 < 4; ++r2)
          vpb[(long)(mb + r2) * 512 + nn] = (__bf16)c[r2];
      } else {
        __bf16* T = qfkfT + (long)(z - 2) * NE;
        const long bb = (long)(mb >> 9) << 18;
        const int l = mb & 511;
        bf16x4 pk;
        pk[0] = (__bf16)c[0]; pk[1] = (__bf16)c[1];
        pk[2] = (__bf16)c[2]; pk[3] = (__bf16)c[3];
        *(bf16x4*)(T + bb + (long)nn * 512 + l) = pk;
      }
    }
  }
}

// mega2: z 0..7 qf2 -> qcat[:,512:], z 8..15 kf2 -> kcat[:,512:], z 16..23 vp2T = NT(Wfc, vp[b])
__global__ __launch_bounds__(256)
void mega2_kernel(const __bf16* __restrict__ featb, const __bf16* __restrict__ qfkfT,
                  const __bf16* __restrict__ Wfcb, const __bf16* __restrict__ vpb,
                  __bf16* __restrict__ qcat, __bf16* __restrict__ kcat,
                  __bf16* __restrict__ vp2T)
{
  __shared__ __align__(16) __bf16 sA[2 * 64 * 32];
  __shared__ __align__(16) __bf16 sB[2 * 128 * 32];
  const int z = blockIdx.z;
  const __bf16 *A, *B;
  __bf16* C;
  int ldc;
  if (z < 16) {
    const int b = z & 7, s = z >> 3;
    A = featb + (long)b * WE;
    B = qfkfT + (long)s * NE + (long)b * WE;
    C = (s ? kcat : qcat) + (long)b * CPL + 512;
    ldc = 1024;
  } else {
    const int b = z - 16;
    A = Wfcb;
    B = vpb + (long)b * WE;
    C = vp2T + (long)b * WE;
    ldc = 512;
  }
  const int m0 = blockIdx.y * 64, n0 = blockIdx.x * 128;
  f32x4 acc[2][4];
  #pragma unroll
  for (int i = 0; i < 2; ++i)
    #pragma unroll
    for (int j = 0; j < 4; ++j) acc[i][j] = 0.0f;
  core_vdb<false>(A, B, 512, m0, n0, sA, sB, acc);

  const int wave = threadIdx.x >> 6, lane = threadIdx.x & 63;
  const int quad = lane >> 4, l16 = lane & 15;
  const int wm = (wave >> 1) * 32, wn = (wave & 1) * 64;
  #pragma unroll
  for (int i = 0; i < 2; ++i) {
    const int mb = m0 + wm + i * 16 + quad * 4;
    #pragma unroll
    for (int j = 0; j < 4; ++j) {
      const int nn = n0 + wn + j * 16 + l16;
      f32x4 c = acc[i][j];
      #pragma unroll
      for (int r2 = 0; r2 < 4; ++r2)
        C[(long)(mb + r2) * ldc + nn] = (__bf16)c[r2];
    }
  }
}

// scores: attn = tanh(mask((qcat . kcat^T)/temp)), K=1024. grid (4,8,8)
__global__ __launch_bounds__(256)
void scores_kernel(const __bf16* __restrict__ qcat, const __bf16* __restrict__ kcat,
                   const int* __restrict__ lens, float* __restrict__ attnf)
{
  __shared__ __align__(16) __bf16 sA[2 * 64 * 32];
  __shared__ __align__(16) __bf16 sB[2 * 128 * 32];
  const int b = blockIdx.z;
  const int len = lens[b];
  const int m0 = blockIdx.y * 64, n0 = blockIdx.x * 128;
  f32x4 acc[2][4];
  #pragma unroll
  for (int i = 0; i < 2; ++i)
    #pragma unroll
    for (int j = 0; j < 4; ++j) acc[i][j] = 0.0f;
  core_vdb<false>(qcat + (long)b * CPL, kcat + (long)b * CPL, 1024, m0, n0, sA, sB, acc);

  const long off = (long)b * WE;
  const int wave = threadIdx.x >> 6, lane = threadIdx.x & 63;
  const int quad = lane >> 4, l16 = lane & 15;
  const int wm = (wave >> 1) * 32, wn = (wave & 1) * 64;
  #pragma unroll
  for (int i = 0; i < 2; ++i) {
    const int mb = m0 + wm + i * 16 + quad * 4;
    #pragma unroll
    for (int j = 0; j < 4; ++j) {
      const int nn = n0 + wn + j * 16 + l16;
      f32x4 c = acc[i][j];
      #pragma unroll
      for (int r2 = 0; r2 < 4; ++r2) {
        float vv = c[r2] * INV_TEMP;
        vv = (nn < len) ? tanhf(vv) : 0.0f;
        attnf[off + (long)(mb + r2) * 512 + nn] = vv;
      }
    }
  }
}

// av2: out2[b] = attn[b] @ vp2[b]; A = attn fp32 (in-register cvt), B = vp2T. grid (4,8,8)
__global__ __launch_bounds__(256)
void av2_kernel(const float* __restrict__ attnf, const __bf16* __restrict__ vp2T,
                float* __restrict__ out2)
{
  __shared__ __align__(16) __bf16 sA[2 * 64 * 32];
  __shared__ __align__(16) __bf16 sB[2 * 128 * 32];
  const int b = blockIdx.z;
  const int m0 = blockIdx.y * 64, n0 = blockIdx.x * 128;
  f32x4 acc[2][4];
  #pragma unroll
  for (int i = 0; i < 2; ++i)
    #pragma unroll
    for (int j = 0; j < 4; ++j) acc[i][j] = 0.0f;
  core_vdb<true>(attnf + (long)b * WE, vp2T + (long)b * WE, 512, m0, n0, sA, sB, acc);

  const long off = (long)b * WE;
  const int wave = threadIdx.x >> 6, lane = threadIdx.x & 63;
  const int quad = lane >> 4, l16 = lane & 15;
  const int wm = (wave >> 1) * 32, wn = (wave & 1) * 64;
  #pragma unroll
  for (int i = 0; i < 2; ++i) {
    const int mb = m0 + wm + i * 16 + quad * 4;
    #pragma unroll
    for (int j = 0; j < 4; ++j) {
      const int nn = n0 + wn + j * 16 + l16;
      f32x4 c = acc[i][j];
      #pragma unroll
      for (int r2 = 0; r2 < 4; ++r2)
        out2[off + (long)(mb + r2) * 512 + nn] = c[r2];
    }
  }
}

// ======== featcvt: y=0 weight fp32->bf16 (6 mats), y=1 feature softmax ========
__global__ __launch_bounds__(256)
void featcvt_kernel(const float* __restrict__ Wq, const float* __restrict__ Wk,
                    const float* __restrict__ Wqf, const float* __restrict__ Wkf,
                    const float* __restrict__ Wv, const float* __restrict__ Wfc,
                    __bf16* __restrict__ Wb,
                    const float* __restrict__ x, const float* __restrict__ imp,
                    const int* __restrict__ lens, __bf16* __restrict__ featb)
{
  __shared__ float xfs[L_ * NF]; // 22.5 KB (feat path)
  const int tid = threadIdx.x;
  const int wave = tid >> 6, lane = tid & 63;
  if (blockIdx.y == 0) {
    const float* srcs[6] = {Wq, Wk, Wqf, Wkf, Wv, Wfc};
    const int gtid = blockIdx.x * 256 + tid; // 0..32767
    #pragma unroll
    for (int a = 0; a < 6; ++a) {
      const float* s = srcs[a];
      __bf16* d = Wb + (long)a * WE;
      #pragma unroll
      for (int r = 0; r < 2; ++r) {
        long i = (long)(gtid + r * 32768) * 4;
        float4 vv = *(const float4*)(s + i);
        bf16x4 o;
        o[0] = (__bf16)vv.x; o[1] = (__bf16)vv.y; o[2] = (__bf16)vv.z; o[3] = (__bf16)vv.w;
        *(bf16x4*)(d + i) = o;
      }
    }
  } else {
    const int b = blockIdx.x >> 4;
    const int i0 = (blockIdx.x & 15) * 32;
    for (int idx = tid; idx < L_ * NF; idx += 256) {
      int j = idx / NF, f = idx - j * NF;
      xfs[idx] = x[((long)b * L_ + j) * D_ + f];
    }
    float im[NF];
    #pragma unroll
    for (int f = 0; f < NF; ++f) im[f] = imp[f];
    const int len = lens[b];
    __syncthreads();
    for (int r = 0; r < 8; ++r) {
      const int i = i0 + wave * 8 + r;
      float xi[NF];
      #pragma unroll
      for (int f = 0; f < NF; ++f) xi[f] = xfs[i * NF + f];
      float l[8];
      float m = -INFINITY;
      #pragma unroll
      for (int t = 0; t < 8; ++t) {
        int j = lane + t * 64;
        float s = 0.f;
        #pragma unroll
        for (int f = 0; f < NF; ++f) s = fmaf(fabsf(xi[f] - xfs[j * NF + f]), im[f], s);
        s = (j < len) ? s : NEGV;
        l[t] = s;
        m = fmaxf(m, s);
      }
      #pragma unroll
      for (int o = 32; o >= 1; o >>= 1) m = fmaxf(m, __shfl_xor(m, o));
      float ssum = 0.f;
      #pragma unroll
      for (int t = 0; t < 8; ++t) { l[t] = expf(l[t] - m); ssum += l[t]; }
      #pragma unroll
      for (int o = 32; o >= 1; o >>= 1) ssum += __shfl_xor(ssum, o);
      float inv = 1.0f / ssum;
      #pragma unroll
      for (int t = 0; t < 8; ++t)
        featb[((long)b * L_ + i) * L_ + lane + t * 64] = (__bf16)(l[t] * inv);
    }
  }
}

// ---------------- LayerNorm: 4 rows per block ----------------
__global__ __launch_bounds__(256) void ln_kernel(const float* __restrict__ xin, const float* __restrict__ res,
                                                 const float* __restrict__ gamma, const float* __restrict__ beta,
                                                 float* __restrict__ out)
{
    const int wave = threadIdx.x >> 6, lane = threadIdx.x & 63;
    const long row = blockIdx.x * 4 + wave;
    float v[8];
    float s = 0.f, ss = 0.f;
    #pragma unroll
    for (int t = 0; t < 8; ++t) {
        float u = xin[row * D_ + lane + t * 64] + res[row * D_ + lane + t * 64];
        v[t] = u; s += u; ss = fmaf(u, u, ss);
    }
    #pragma unroll
    for (int o = 32; o >= 1; o >>= 1) { s += __shfl_xor(s, o); ss += __shfl_xor(ss, o); }
    const float mu = s * (1.0f / D_);
    const float var = ss * (1.0f / D_) - mu * mu;
    const float inv = 1.0f / sqrtf(var + 1e-6f);
    #pragma unroll
    for (int t = 0; t < 8; ++t) {
        int d = lane + t * 64;
        out[row * D_ + d] = (v[t] - mu) * inv * gamma[d] + beta[d];
    }
}

extern "C" void kernel_launch(void* const* d_in, const int* in_sizes, int n_in,
                              void* d_out, int out_size, void* d_ws, size_t ws_size,
                              hipStream_t stream) {
    const float* q     = (const float*)d_in[0];
    const float* k     = (const float*)d_in[1];
    const float* v     = (const float*)d_in[2];
    const float* x     = (const float*)d_in[3];
    const int*   lens  = (const int*)d_in[4];
    const float* Wq    = (const float*)d_in[5];
    const float* Wk    = (const float*)d_in[6];
    const float* Wv    = (const float*)d_in[7];
    const float* Wqf   = (const float*)d_in[8];
    const float* Wkf   = (const float*)d_in[9];
    const float* Wfc   = (const float*)d_in[10];
    const float* imp   = (const float*)d_in[11];
    const float* gamma = (const float*)d_in[12];
    const float* beta  = (const float*)d_in[13];

    constexpr long MB = 1 << 20;
    char* w = (char*)d_ws;
    __bf16* Wb    = (__bf16*)(w);            //  0.. 3MB : Wq,Wk,Wqf,Wkf,Wv,Wfc bf16
    __bf16* qfkfT = (__bf16*)(w + 3 * MB);   //  3..11MB : qfT,kfT
    __bf16* vpb   = (__bf16*)(w + 11 * MB);  // 11..15MB : vp
    __bf16* vp2T  = (__bf16*)(w + 15 * MB);  // 15..19MB : vp2T
    __bf16* qcat  = (__bf16*)(w + 19 * MB);  // 19..27MB : [qp | qf2] K=1024
    __bf16* kcat  = (__bf16*)(w + 27 * MB);  // 27..35MB : [kp | kf2]
    float*  out2  = (float*)(w + 35 * MB);   // 35..43MB : pre-LN fp32
    __bf16* featb = (__bf16*)(w + 43 * MB);  // 43..47MB : feat_attn bf16

    float*  outp  = (float*)d_out;           // output 0 [B,L,D]
    float*  attnf = outp + NE;               // output 1 [B,L,L]

    // 1) weight cvt (y=0) + feature softmax (y=1)
    featcvt_kernel<<<dim3(128, 2), 256, 0, stream>>>(Wq, Wk, Wqf, Wkf, Wv, Wfc, Wb,
                                                     x, imp, lens, featb);

    // 2) 5 projections, A fp32 direct via VGPR->LDS pipeline (1280 blocks)
    proj_kernel<<<dim3(4, 64, 5), 256, 0, stream>>>(q, k, v, Wb, qcat, kcat, qfkfT, vpb);

    // 3) qf2,kf2 -> cat right halves + vp2T = Wfc.vp^T (768 blocks)
    mega2_kernel<<<dim3(4, 8, 24), 256, 0, stream>>>(featb, qfkfT, Wb + 5 * WE, vpb,
                                                     qcat, kcat, vp2T);

    // 4) attn = tanh(mask(qcat.kcat^T / temp)), K=1024 (256 blocks)
    scores_kernel<<<dim3(4, 8, 8), 256, 0, stream>>>(qcat, kcat, lens, attnf);

    // 5) out2 = attn @ vp2, A fp32 direct (256 blocks)
    av2_kernel<<<dim3(4, 8, 8), 256, 0, stream>>>(attnf, vp2T, out2);

    // 6) LayerNorm(out2 + q)
    ln_kernel<<<1024, 256, 0, stream>>>(out2, q, gamma, beta, outp);
}

// Round 9
// 181.624 us; speedup vs baseline: 2.3750x; 1.0226x over previous
//
#include <hip/hip_runtime.h>
#include <math.h>

typedef __bf16 bf16x8 __attribute__((ext_vector_type(8)));
typedef __bf16 bf16x4 __attribute__((ext_vector_type(4)));
typedef float  f32x4  __attribute__((ext_vector_type(4)));

namespace {
constexpr int L_ = 512, D_ = 512, NF = 11;
constexpr long WE = (long)L_ * L_;   // 262144 elems, one 512x512 plane
constexpr long NE = 8 * WE;          // 2097152 elems, B*L*D
constexpr long CPL = 512L * 1024;    // concatenated plane (512 rows x 1024)
constexpr float NEGV = -1.0e9f;
constexpr float INV_TEMP = 0.044194173824159216f; // 1/sqrt(512)
}

__device__ __forceinline__ bf16x8 cvt2(float4 a0, float4 a1) {
  bf16x8 f;
  f[0] = (__bf16)a0.x; f[1] = (__bf16)a0.y; f[2] = (__bf16)a0.z; f[3] = (__bf16)a0.w;
  f[4] = (__bf16)a1.x; f[5] = (__bf16)a1.y; f[6] = (__bf16)a1.z; f[7] = (__bf16)a1.w;
  return f;
}

// ======== 64x128 NT core, BK=64 (two 32-col panels), VGPR-prefetch staging ========
// A and/or B may be fp32 (converted in-register before ds_write; same RNE points
// as a separate pre-conversion pass).
template<bool AF32, bool BF32>
__device__ __forceinline__ void core128(const void* Av, const void* Bv,
                                        int K, int m0, int n0,
                                        __bf16* sA, __bf16* sB, f32x4 (&acc)[2][4])
{
  const int tid = threadIdx.x;
  const int wave = tid >> 6, lane = tid & 63;
  const int srow = tid >> 2, scol = (tid & 3) * 8;
  const int quad = lane >> 4, l16 = lane & 15;
  const int wm = (wave >> 1) * 32, wn = (wave & 1) * 64;
  const float*  gAf = (const float*)Av  + (long)(m0 + srow) * K + scol;
  const __bf16* gAb = (const __bf16*)Av + (long)(m0 + srow) * K + scol;
  const float*  gBf = (const float*)Bv  + (long)(n0 + srow) * K + scol;
  const __bf16* gBb = (const __bf16*)Bv + (long)(n0 + srow) * K + scol;
  __bf16* dA = sA + srow * 32 + scol;   // sA: [2][64][32]  panel stride 2048
  __bf16* dB = sB + srow * 32 + scol;   // sB: [2][128][32] panel stride 4096

  float4 fa[2][2]; bf16x8 ba[2];
  float4 fb[4][2]; bf16x8 rb[4];
  const long bofs[4] = {0, 32, (long)64 * K, (long)64 * K + 32};

  // tile-0 prefetch
  if (AF32) {
    fa[0][0] = *(const float4*)(gAf);      fa[0][1] = *(const float4*)(gAf + 4);
    fa[1][0] = *(const float4*)(gAf + 32); fa[1][1] = *(const float4*)(gAf + 36);
  } else {
    ba[0] = *(const bf16x8*)(gAb);
    ba[1] = *(const bf16x8*)(gAb + 32);
  }
  #pragma unroll
  for (int c = 0; c < 4; ++c) {
    if (BF32) { fb[c][0] = *(const float4*)(gBf + bofs[c]); fb[c][1] = *(const float4*)(gBf + bofs[c] + 4); }
    else      { rb[c] = *(const bf16x8*)(gBb + bofs[c]); }
  }

  const int dBo[4] = {0, 4096, 64 * 32, 4096 + 64 * 32};
  for (int k0 = 0; k0 < K; k0 += 64) {
    __syncthreads();                 // all waves done reading previous LDS tile
    {
      bf16x8 wa0, wa1;
      if (AF32) { wa0 = cvt2(fa[0][0], fa[0][1]); wa1 = cvt2(fa[1][0], fa[1][1]); }
      else      { wa0 = ba[0]; wa1 = ba[1]; }
      *(bf16x8*)(dA)        = wa0;
      *(bf16x8*)(dA + 2048) = wa1;
      #pragma unroll
      for (int c = 0; c < 4; ++c) {
        bf16x8 wb;
        if (BF32) wb = cvt2(fb[c][0], fb[c][1]);
        else      wb = rb[c];
        *(bf16x8*)(dB + dBo[c]) = wb;
      }
    }
    __syncthreads();                 // writes visible
    if (k0 + 64 < K) {               // issue next tile's loads; waits land next iter
      const int kn = k0 + 64;
      if (AF32) {
        fa[0][0] = *(const float4*)(gAf + kn);      fa[0][1] = *(const float4*)(gAf + kn + 4);
        fa[1][0] = *(const float4*)(gAf + kn + 32); fa[1][1] = *(const float4*)(gAf + kn + 36);
      } else {
        ba[0] = *(const bf16x8*)(gAb + kn);
        ba[1] = *(const bf16x8*)(gAb + kn + 32);
      }
      #pragma unroll
      for (int c = 0; c < 4; ++c) {
        if (BF32) { fb[c][0] = *(const float4*)(gBf + kn + bofs[c]); fb[c][1] = *(const float4*)(gBf + kn + bofs[c] + 4); }
        else      { rb[c] = *(const bf16x8*)(gBb + kn + bofs[c]); }
      }
    }
    #pragma unroll
    for (int p = 0; p < 2; ++p) {
      bf16x8 af[2], bfr[4];
      #pragma unroll
      for (int i = 0; i < 2; ++i)
        af[i]  = *(const bf16x8*)(sA + p * 2048 + (wm + i * 16 + l16) * 32 + quad * 8);
      #pragma unroll
      for (int j = 0; j < 4; ++j)
        bfr[j] = *(const bf16x8*)(sB + p * 4096 + (wn + j * 16 + l16) * 32 + quad * 8);
      #pragma unroll
      for (int i = 0; i < 2; ++i)
        #pragma unroll
        for (int j = 0; j < 4; ++j)
          acc[i][j] = __builtin_amdgcn_mfma_f32_16x16x32_bf16(af[i], bfr[j], acc[i][j], 0, 0, 0);
    }
  }
}

// ======== 64x64 NT core, BK=64 panels, VGPR-prefetch (scores / av2) ========
template<bool AF32>
__device__ __forceinline__ void core64(const void* Av, const __bf16* __restrict__ B,
                                       int K, int m0, int n0,
                                       __bf16* sA, __bf16* sB, f32x4 (&acc)[2][2])
{
  const int tid = threadIdx.x;
  const int wave = tid >> 6, lane = tid & 63;
  const int srow = tid >> 2, scol = (tid & 3) * 8;
  const int quad = lane >> 4, l16 = lane & 15;
  const int wm = (wave >> 1) * 32, wn = (wave & 1) * 32;
  const float*  gAf = (const float*)Av  + (long)(m0 + srow) * K + scol;
  const __bf16* gAb = (const __bf16*)Av + (long)(m0 + srow) * K + scol;
  const __bf16* gB  = B + (long)(n0 + srow) * K + scol;
  __bf16* dA = sA + srow * 32 + scol;   // [2][64][32] panel stride 2048
  __bf16* dB = sB + srow * 32 + scol;

  float4 fa[2][2]; bf16x8 ba[2];
  bf16x8 rb[2];

  if (AF32) {
    fa[0][0] = *(const float4*)(gAf);      fa[0][1] = *(const float4*)(gAf + 4);
    fa[1][0] = *(const float4*)(gAf + 32); fa[1][1] = *(const float4*)(gAf + 36);
  } else {
    ba[0] = *(const bf16x8*)(gAb);
    ba[1] = *(const bf16x8*)(gAb + 32);
  }
  rb[0] = *(const bf16x8*)(gB);
  rb[1] = *(const bf16x8*)(gB + 32);

  for (int k0 = 0; k0 < K; k0 += 64) {
    __syncthreads();
    {
      bf16x8 wa0, wa1;
      if (AF32) { wa0 = cvt2(fa[0][0], fa[0][1]); wa1 = cvt2(fa[1][0], fa[1][1]); }
      else      { wa0 = ba[0]; wa1 = ba[1]; }
      *(bf16x8*)(dA)        = wa0;
      *(bf16x8*)(dA + 2048) = wa1;
      *(bf16x8*)(dB)        = rb[0];
      *(bf16x8*)(dB + 2048) = rb[1];
    }
    __syncthreads();
    if (k0 + 64 < K) {
      const int kn = k0 + 64;
      if (AF32) {
        fa[0][0] = *(const float4*)(gAf + kn);      fa[0][1] = *(const float4*)(gAf + kn + 4);
        fa[1][0] = *(const float4*)(gAf + kn + 32); fa[1][1] = *(const float4*)(gAf + kn + 36);
      } else {
        ba[0] = *(const bf16x8*)(gAb + kn);
        ba[1] = *(const bf16x8*)(gAb + kn + 32);
      }
      rb[0] = *(const bf16x8*)(gB + kn);
      rb[1] = *(const bf16x8*)(gB + kn + 32);
    }
    #pragma unroll
    for (int p = 0; p < 2; ++p) {
      bf16x8 af[2], bfr[2];
      #pragma unroll
      for (int i = 0; i < 2; ++i)
        af[i]  = *(const bf16x8*)(sA + p * 2048 + (wm + i * 16 + l16) * 32 + quad * 8);
      #pragma unroll
      for (int j = 0; j < 2; ++j)
        bfr[j] = *(const bf16x8*)(sB + p * 2048 + (wn + j * 16 + l16) * 32 + quad * 8);
      #pragma unroll
      for (int i = 0; i < 2; ++i)
        #pragma unroll
        for (int j = 0; j < 2; ++j)
          acc[i][j] = __builtin_amdgcn_mfma_f32_16x16x32_bf16(af[i], bfr[j], acc[i][j], 0, 0, 0);
    }
  }
}

// ======== proj+feat: z<5 projections (A,B fp32 direct), z=5 feature softmax ========
// z: 0=qp->qcat[:,:512] 1=kp->kcat[:,:512] 2=qfT 3=kfT 4=vp
__global__ __launch_bounds__(256)
void proj_kernel(const float* __restrict__ q, const float* __restrict__ k,
                 const float* __restrict__ v,
                 const float* __restrict__ Wq, const float* __restrict__ Wk,
                 const float* __restrict__ Wqf, const float* __restrict__ Wkf,
                 const float* __restrict__ Wv,
                 const float* __restrict__ x, const float* __restrict__ imp,
                 const int* __restrict__ lens,
                 __bf16* __restrict__ qcat, __bf16* __restrict__ kcat,
                 __bf16* __restrict__ qfkfT, __bf16* __restrict__ vpb,
                 __bf16* __restrict__ featb)
{
  __shared__ __align__(16) char smem[24576]; // GEMM: sA 8K + sB 16K; feat: 22.5K
  const int z = blockIdx.z;
  const int tid = threadIdx.x;
  const int wave = tid >> 6, lane = tid & 63;

  if (z < 5) {
    __bf16* sA = (__bf16*)smem;
    __bf16* sB = sA + 2 * 64 * 32;
    const float* As[5] = {q, k, q, k, v};
    const float* Bs[5] = {Wq, Wk, Wqf, Wkf, Wv};
    const int m0 = blockIdx.y * 64, n0 = blockIdx.x * 128;
    f32x4 acc[2][4];
    #pragma unroll
    for (int i = 0; i < 2; ++i)
      #pragma unroll
      for (int j = 0; j < 4; ++j) acc[i][j] = 0.0f;
    core128<true, true>(As[z], Bs[z], 512, m0, n0, sA, sB, acc);

    const int quad = lane >> 4, l16 = lane & 15;
    const int wm = (wave >> 1) * 32, wn = (wave & 1) * 64;
    #pragma unroll
    for (int i = 0; i < 2; ++i) {
      const int mb = m0 + wm + i * 16 + quad * 4;
      #pragma unroll
      for (int j = 0; j < 4; ++j) {
        const int nn = n0 + wn + j * 16 + l16;
        f32x4 c = acc[i][j];
        if (z < 2) {
          __bf16* C = (z == 0) ? qcat : kcat;
          #pragma unroll
          for (int r2 = 0; r2 < 4; ++r2)
            C[(long)(mb + r2) * 1024 + nn] = (__bf16)c[r2];
        } else if (z == 4) {
          #pragma unroll
          for (int r2 = 0; r2 < 4; ++r2)
            vpb[(long)(mb + r2) * 512 + nn] = (__bf16)c[r2];
        } else {
          __bf16* T = qfkfT + (long)(z - 2) * NE;
          const long bb = (long)(mb >> 9) << 18;
          const int l = mb & 511;
          bf16x4 pk;
          pk[0] = (__bf16)c[0]; pk[1] = (__bf16)c[1];
          pk[2] = (__bf16)c[2]; pk[3] = (__bf16)c[3];
          *(bf16x4*)(T + bb + (long)nn * 512 + l) = pk;
        }
      }
    }
  } else {
    const int flat = blockIdx.y * 4 + blockIdx.x; // 0..255
    if (flat >= 128) return;
    float* xfs = (float*)smem; // 22.5 KB
    const int b = flat >> 4;
    const int i0 = (flat & 15) * 32;
    for (int idx = tid; idx < L_ * NF; idx += 256) {
      int j = idx / NF, f = idx - j * NF;
      xfs[idx] = x[((long)b * L_ + j) * D_ + f];
    }
    float im[NF];
    #pragma unroll
    for (int f = 0; f < NF; ++f) im[f] = imp[f];
    const int len = lens[b];
    __syncthreads();
    for (int r = 0; r < 8; ++r) {
      const int i = i0 + wave * 8 + r;
      float xi[NF];
      #pragma unroll
      for (int f = 0; f < NF; ++f) xi[f] = xfs[i * NF + f];
      float l[8];
      float m = -INFINITY;
      #pragma unroll
      for (int t = 0; t < 8; ++t) {
        int j = lane + t * 64;
        float s = 0.f;
        #pragma unroll
        for (int f = 0; f < NF; ++f) s = fmaf(fabsf(xi[f] - xfs[j * NF + f]), im[f], s);
        s = (j < len) ? s : NEGV;
        l[t] = s;
        m = fmaxf(m, s);
      }
      #pragma unroll
      for (int o = 32; o >= 1; o >>= 1) m = fmaxf(m, __shfl_xor(m, o));
      float ssum = 0.f;
      #pragma unroll
      for (int t = 0; t < 8; ++t) { l[t] = expf(l[t] - m); ssum += l[t]; }
      #pragma unroll
      for (int o = 32; o >= 1; o >>= 1) ssum += __shfl_xor(ssum, o);
      float inv = 1.0f / ssum;
      #pragma unroll
      for (int t = 0; t < 8; ++t)
        featb[((long)b * L_ + i) * L_ + lane + t * 64] = (__bf16)(l[t] * inv);
    }
  }
}

// mega2: z 0..7 qf2 -> qcat[:,512:], z 8..15 kf2 -> kcat[:,512:], z 16..23 vp2T = NT(Wfc, vp[b])
__global__ __launch_bounds__(256)
void mega2_kernel(const __bf16* __restrict__ featb, const __bf16* __restrict__ qfkfT,
                  const float* __restrict__ Wfc, const __bf16* __restrict__ vpb,
                  __bf16* __restrict__ qcat, __bf16* __restrict__ kcat,
                  __bf16* __restrict__ vp2T)
{
  __shared__ __align__(16) __bf16 sA[2 * 64 * 32];
  __shared__ __align__(16) __bf16 sB[2 * 128 * 32];
  const int z = blockIdx.z;
  const int m0 = blockIdx.y * 64, n0 = blockIdx.x * 128;
  f32x4 acc[2][4];
  #pragma unroll
  for (int i = 0; i < 2; ++i)
    #pragma unroll
    for (int j = 0; j < 4; ++j) acc[i][j] = 0.0f;

  __bf16* C;
  int ldc;
  if (z < 16) {
    const int b = z & 7, s = z >> 3;
    const __bf16* A = featb + (long)b * WE;
    const __bf16* B = qfkfT + (long)s * NE + (long)b * WE;
    C = (s ? kcat : qcat) + (long)b * CPL + 512;
    ldc = 1024;
    core128<false, false>(A, B, 512, m0, n0, sA, sB, acc);
  } else {
    const int b = z - 16;
    const __bf16* B = vpb + (long)b * WE;
    C = vp2T + (long)b * WE;
    ldc = 512;
    core128<true, false>(Wfc, B, 512, m0, n0, sA, sB, acc);
  }

  const int wave = threadIdx.x >> 6, lane = threadIdx.x & 63;
  const int quad = lane >> 4, l16 = lane & 15;
  const int wm = (wave >> 1) * 32, wn = (wave & 1) * 64;
  #pragma unroll
  for (int i = 0; i < 2; ++i) {
    const int mb = m0 + wm + i * 16 + quad * 4;
    #pragma unroll
    for (int j = 0; j < 4; ++j) {
      const int nn = n0 + wn + j * 16 + l16;
      f32x4 c = acc[i][j];
      #pragma unroll
      for (int r2 = 0; r2 < 4; ++r2)
        C[(long)(mb + r2) * ldc + nn] = (__bf16)c[r2];
    }
  }
}

// scores: attn = tanh(mask((qcat . kcat^T)/temp)), K=1024, 64x64 tiles, grid (8,8,8)
__global__ __launch_bounds__(256)
void scores_kernel(const __bf16* __restrict__ qcat, const __bf16* __restrict__ kcat,
                   const int* __restrict__ lens, float* __restrict__ attnf)
{
  __shared__ __align__(16) __bf16 sA[2 * 64 * 32];
  __shared__ __align__(16) __bf16 sB[2 * 64 * 32];
  const int b = blockIdx.z;
  const int len = lens[b];
  const int m0 = blockIdx.y * 64, n0 = blockIdx.x * 64;
  f32x4 acc[2][2];
  #pragma unroll
  for (int i = 0; i < 2; ++i)
    #pragma unroll
    for (int j = 0; j < 2; ++j) acc[i][j] = 0.0f;
  core64<false>(qcat + (long)b * CPL, kcat + (long)b * CPL, 1024, m0, n0, sA, sB, acc);

  const long off = (long)b * WE;
  const int wave = threadIdx.x >> 6, lane = threadIdx.x & 63;
  const int quad = lane >> 4, l16 = lane & 15;
  const int wm = (wave >> 1) * 32, wn = (wave & 1) * 32;
  #pragma unroll
  for (int i = 0; i < 2; ++i) {
    const int mb = m0 + wm + i * 16 + quad * 4;
    #pragma unroll
    for (int j = 0; j < 2; ++j) {
      const int nn = n0 + wn + j * 16 + l16;
      f32x4 c = acc[i][j];
      #pragma unroll
      for (int r2 = 0; r2 < 4; ++r2) {
        float vv = c[r2] * INV_TEMP;
        vv = (nn < len) ? tanhf(vv) : 0.0f;
        attnf[off + (long)(mb + r2) * 512 + nn] = vv;
      }
    }
  }
}

// av2: out2[b] = attn[b] @ vp2[b]; A = attn fp32 direct, 64x64 tiles, grid (8,8,8)
__global__ __launch_bounds__(256)
void av2_kernel(const float* __restrict__ attnf, const __bf16* __restrict__ vp2T,
                float* __restrict__ out2)
{
  __shared__ __align__(16) __bf16 sA[2 * 64 * 32];
  __shared__ __align__(16) __bf16 sB[2 * 64 * 32];
  const int b = blockIdx.z;
  const int m0 = blockIdx.y * 64, n0 = blockIdx.x * 64;
  f32x4 acc[2][2];
  #pragma unroll
  for (int i = 0; i < 2; ++i)
    #pragma unroll
    for (int j = 0; j < 2; ++j) acc[i][j] = 0.0f;
  core64<true>(attnf + (long)b * WE, vp2T + (long)b * WE, 512, m0, n0, sA, sB, acc);

  const long off = (long)b * WE;
  const int wave = threadIdx.x >> 6, lane = threadIdx.x & 63;
  const int quad = lane >> 4, l16 = lane & 15;
  const int wm = (wave >> 1) * 32, wn = (wave & 1) * 32;
  #pragma unroll
  for (int i = 0; i < 2; ++i) {
    const int mb = m0 + wm + i * 16 + quad * 4;
    #pragma unroll
    for (int j = 0; j < 2; ++j) {
      const int nn = n0 + wn + j * 16 + l16;
      f32x4 c = acc[i][j];
      #pragma unroll
      for (int r2 = 0; r2 < 4; ++r2)
        out2[off + (long)(mb + r2) * 512 + nn] = c[r2];
    }
  }
}

// ---------------- LayerNorm: 4 rows per block ----------------
__global__ __launch_bounds__(256) void ln_kernel(const float* __restrict__ xin, const float* __restrict__ res,
                                                 const float* __restrict__ gamma, const float* __restrict__ beta,
                                                 float* __restrict__ out)
{
    const int wave = threadIdx.x >> 6, lane = threadIdx.x & 63;
    const long row = blockIdx.x * 4 + wave;
    float v[8];
    float s = 0.f, ss = 0.f;
    #pragma unroll
    for (int t = 0; t < 8; ++t) {
        float u = xin[row * D_ + lane + t * 64] + res[row * D_ + lane + t * 64];
        v[t] = u; s += u; ss = fmaf(u, u, ss);
    }
    #pragma unroll
    for (int o = 32; o >= 1; o >>= 1) { s += __shfl_xor(s, o); ss += __shfl_xor(ss, o); }
    const float mu = s * (1.0f / D_);
    const float var = ss * (1.0f / D_) - mu * mu;
    const float inv = 1.0f / sqrtf(var + 1e-6f);
    #pragma unroll
    for (int t = 0; t < 8; ++t) {
        int d = lane + t * 64;
        out[row * D_ + d] = (v[t] - mu) * inv * gamma[d] + beta[d];
    }
}

extern "C" void kernel_launch(void* const* d_in, const int* in_sizes, int n_in,
                              void* d_out, int out_size, void* d_ws, size_t ws_size,
                              hipStream_t stream) {
    const float* q     = (const float*)d_in[0];
    const float* k     = (const float*)d_in[1];
    const float* v     = (const float*)d_in[2];
    const float* x     = (const float*)d_in[3];
    const int*   lens  = (const int*)d_in[4];
    const float* Wq    = (const float*)d_in[5];
    const float* Wk    = (const float*)d_in[6];
    const float* Wv    = (const float*)d_in[7];
    const float* Wqf   = (const float*)d_in[8];
    const float* Wkf   = (const float*)d_in[9];
    const float* Wfc   = (const float*)d_in[10];
    const float* imp   = (const float*)d_in[11];
    const float* gamma = (const float*)d_in[12];
    const float* beta  = (const float*)d_in[13];

    constexpr long MB = 1 << 20;
    char* w = (char*)d_ws;
    __bf16* qfkfT = (__bf16*)(w);            //  0.. 8MB : qfT,kfT
    __bf16* vpb   = (__bf16*)(w + 8 * MB);   //  8..12MB : vp
    __bf16* vp2T  = (__bf16*)(w + 12 * MB);  // 12..16MB : vp2T
    __bf16* qcat  = (__bf16*)(w + 16 * MB);  // 16..24MB : [qp | qf2] K=1024
    __bf16* kcat  = (__bf16*)(w + 24 * MB);  // 24..32MB : [kp | kf2]
    float*  out2  = (float*)(w + 32 * MB);   // 32..40MB : pre-LN fp32
    __bf16* featb = (__bf16*)(w + 40 * MB);  // 40..44MB : feat_attn bf16

    float*  outp  = (float*)d_out;           // output 0 [B,L,D]
    float*  attnf = outp + NE;               // output 1 [B,L,L]

    // 1) 5 projections (fp32 A and B, in-register cvt) + feature softmax (z=5)
    proj_kernel<<<dim3(4, 64, 6), 256, 0, stream>>>(q, k, v, Wq, Wk, Wqf, Wkf, Wv,
                                                    x, imp, lens,
                                                    qcat, kcat, qfkfT, vpb, featb);

    // 2) qf2,kf2 -> cat right halves + vp2T = Wfc.vp^T (768 blocks)
    mega2_kernel<<<dim3(4, 8, 24), 256, 0, stream>>>(featb, qfkfT, Wfc, vpb,
                                                     qcat, kcat, vp2T);

    // 3) attn = tanh(mask(qcat.kcat^T / temp)), K=1024 (512 blocks, 64x64)
    scores_kernel<<<dim3(8, 8, 8), 256, 0, stream>>>(qcat, kcat, lens, attnf);

    // 4) out2 = attn @ vp2, A fp32 direct (512 blocks, 64x64)
    av2_kernel<<<dim3(8, 8, 8), 256, 0, stream>>>(attnf, vp2T, out2);

    // 5) LayerNorm(out2 + q)
    ln_kernel<<<1024, 256, 0, stream>>>(out2, q, gamma, beta, outp);
}